// Round 11
// baseline (872.896 us; speedup 1.0000x reference)
//
#include <hip/hip_runtime.h>

#define NROWS 262144
#define KDIM  512
#define ODIM  128

typedef __attribute__((ext_vector_type(8))) __bf16 bf16x8;
typedef __attribute__((ext_vector_type(4))) float  f32x4;

typedef __attribute__((address_space(1))) const unsigned int* gas_u32p;
typedef __attribute__((address_space(3))) unsigned int*       las_u32p;

// ---- workspace layout (bytes) ----
// [0      , 262144): Wp  packed split-bf16 W, 16 kc-slices x 16KB (see R4 note:
//   XOR swizzle baked into GLOBAL chunk order; LDS staging stays linear).
// [262144, 278528): partials double[2048]
// [278528, 279552): counts  int[256]
// [279552, 280576): offsets int[256]

// ---------------- W pre-convert: fp32 -> packed swizzled (hi,lo) ----------------
__global__ __launch_bounds__(256) void convert_w_kernel(
    const float* __restrict__ W, char* __restrict__ WpB) {
  int gid = blockIdx.x * 256 + threadIdx.x;  // 8192 threads: kc(16) x r(128) x kg(4)
  int kg = gid & 3, r = (gid >> 2) & 127, kc = gid >> 9;
  const float4* src = (const float4*)(W + (size_t)r * KDIM + kc * 32 + kg * 8);
  float4 v0 = src[0], v1 = src[1];
  float f[8] = {v0.x, v0.y, v0.z, v0.w, v1.x, v1.y, v1.z, v1.w};
  bf16x8 h, l;
#pragma unroll
  for (int e = 0; e < 8; ++e) {
    __bf16 hh = (__bf16)f[e];
    h[e] = hh;
    l[e] = (__bf16)(f[e] - (float)hh);  // residual exact in fp32, then RNE
  }
  char* slice = WpB + (size_t)kc * 16384 + r * 128;  // r*8 chunks * 16B
  int swz = r & 7;
  *(bf16x8*)(slice + ((kg ^ swz)) * 16)       = h;
  *(bf16x8*)(slice + (((4 + kg) ^ swz)) * 16) = l;
}

// ---------------- GEMM: out = x @ W^T + b, split-bf16 3-MFMA ----------------
// R9 post-mortem: counted-vmcnt (T4) was total-neutral -- at ~12 waves/CU and
// MfmaUtil ~10-20% the implicit wave overlap already hides the barrier drain
// (documented m99/m100 lesson). Remaining gap (GEMM ~190us vs 102 floor) is
// attributed to x-stream DRAM granularity: K-major consumption touches each
// 2KB row 16x at 128B/touch, ~1900cy apart (no page locality). R10: A-loads
// chunked 2 kc at a time -> 256B contiguous per row-touch, 8 touches/row.
// vmcnt ledger (16 ops outstanding at each wait): even kc waits vmcnt(4)
// (oldest 12 = stage(kc)+loadA(chunk)), odd kc waits vmcnt(12) (oldest 4 =
// stage(kc)). Prologue {loadA 8, stage 4, stage 4} matches. B pipeline,
// barriers, MFMA order, numerics identical to benched lineage (absmax .0156).
__global__ __launch_bounds__(256, 3) void gemm_kernel(
    const float* __restrict__ x, const char* __restrict__ WpB,
    const float* __restrict__ bias, float* __restrict__ out,
    double* __restrict__ partials) {
  const int lane = threadIdx.x & 63;
  const int wid  = threadIdx.x >> 6;
  const int ncol = lane & 15;
  const int kg   = lane >> 4;  // k-subgroup 0..3 (8 elems each)

  __shared__ __align__(16) char lds[49152];  // 3 x 16KB B-slice buffers

  const int row0 = blockIdx.x * 128 + wid * 32 + ncol;  // A rows, subtile 0
  const float* xrow0 = x + (size_t)row0 * KDIM + kg * 8;
  const float* xrow1 = xrow0 + (size_t)16 * KDIM;

  f32x4 acc[2][8];
#pragma unroll
  for (int rs = 0; rs < 2; ++rs)
#pragma unroll
    for (int ct = 0; ct < 8; ++ct) acc[rs][ct] = (f32x4){0.f, 0.f, 0.f, 0.f};

  // A chunk buffers: [rs][kc_in_chunk*8 + e], chunk = 2 kc = 256B/row touch.
  float a_cur[2][16], a_nxt[2][16];

  // ---- prologue: loadA chunk0 (8 ops); stage slice0; stage slice1 ----
#pragma unroll
  for (int rs = 0; rs < 2; ++rs) {
    const float4* p = (const float4*)(rs ? xrow1 : xrow0);
    float4 q0 = p[0], q1 = p[1];        // kc=0
    float4 q2 = p[8], q3 = p[9];        // kc=1 (+32 floats = +8 float4)
    a_cur[rs][0]=q0.x; a_cur[rs][1]=q0.y; a_cur[rs][2]=q0.z; a_cur[rs][3]=q0.w;
    a_cur[rs][4]=q1.x; a_cur[rs][5]=q1.y; a_cur[rs][6]=q1.z; a_cur[rs][7]=q1.w;
    a_cur[rs][8]=q2.x; a_cur[rs][9]=q2.y; a_cur[rs][10]=q2.z; a_cur[rs][11]=q2.w;
    a_cur[rs][12]=q3.x; a_cur[rs][13]=q3.y; a_cur[rs][14]=q3.z; a_cur[rs][15]=q3.w;
  }
#pragma unroll
  for (int s = 0; s < 2; ++s) {
#pragma unroll
    for (int i = 0; i < 4; ++i) {
      const int cbase = (wid * 4 + i) * 64;  // wave-uniform chunk base
      __builtin_amdgcn_global_load_lds(
          (gas_u32p)(WpB + (size_t)s * 16384 + (size_t)(cbase + lane) * 16),
          (las_u32p)(lds + s * 16384 + cbase * 16), 16, 0, 0);
    }
  }

  int cb = 0;  // compute buffer (rotates per kc)
  int sb = 2;  // stage buffer
#pragma unroll 2
  for (int s = 0; s < 8; ++s) {
    // ================= even half: kc = 2s =================
    asm volatile("s_waitcnt vmcnt(4)" ::: "memory");
    asm volatile("s_barrier" ::: "memory");
    {
      bf16x8 ah[2], al[2];
#pragma unroll
      for (int rs = 0; rs < 2; ++rs)
#pragma unroll
        for (int e = 0; e < 8; ++e) {
          float f = a_cur[rs][e];
          __bf16 h = (__bf16)f;
          ah[rs][e] = h;
          al[rs][e] = (__bf16)(f - (float)h);
        }
      const char* cur = lds + cb * 16384;
#pragma unroll
      for (int ct = 0; ct < 8; ++ct) {
        const int r   = ct * 16 + ncol;
        const int swz = r & 7;
        bf16x8 bh = *(const bf16x8*)(cur + (size_t)(r * 8 + (kg ^ swz)) * 16);
        bf16x8 bl = *(const bf16x8*)(cur + (size_t)(r * 8 + ((4 + kg) ^ swz)) * 16);
#pragma unroll
        for (int rs = 0; rs < 2; ++rs) {
          acc[rs][ct] = __builtin_amdgcn_mfma_f32_16x16x32_bf16(ah[rs], bh, acc[rs][ct], 0, 0, 0);
          acc[rs][ct] = __builtin_amdgcn_mfma_f32_16x16x32_bf16(al[rs], bh, acc[rs][ct], 0, 0, 0);
          acc[rs][ct] = __builtin_amdgcn_mfma_f32_16x16x32_bf16(ah[rs], bl, acc[rs][ct], 0, 0, 0);
        }
      }
    }
    // loadA chunk s+1 (8 ops; clamped redundant re-load on last super-iter)
    {
      const int coff = ((s < 7) ? (s + 1) : 7) * 64;  // floats
#pragma unroll
      for (int rs = 0; rs < 2; ++rs) {
        const float4* p = (const float4*)((rs ? xrow1 : xrow0) + coff);
        float4 q0 = p[0], q1 = p[1], q2 = p[8], q3 = p[9];
        a_nxt[rs][0]=q0.x; a_nxt[rs][1]=q0.y; a_nxt[rs][2]=q0.z; a_nxt[rs][3]=q0.w;
        a_nxt[rs][4]=q1.x; a_nxt[rs][5]=q1.y; a_nxt[rs][6]=q1.z; a_nxt[rs][7]=q1.w;
        a_nxt[rs][8]=q2.x; a_nxt[rs][9]=q2.y; a_nxt[rs][10]=q2.z; a_nxt[rs][11]=q2.w;
        a_nxt[rs][12]=q3.x; a_nxt[rs][13]=q3.y; a_nxt[rs][14]=q3.z; a_nxt[rs][15]=q3.w;
      }
    }
    // stage(2s+2) (4 ops; &15 wrap -> tail dummies hit only dead buffers)
    {
      const char* gsrc = WpB + (size_t)((2 * s + 2) & 15) * 16384;
      char* dst = lds + sb * 16384;
#pragma unroll
      for (int i = 0; i < 4; ++i) {
        const int cbase = (wid * 4 + i) * 64;
        __builtin_amdgcn_global_load_lds(
            (gas_u32p)(gsrc + (size_t)(cbase + lane) * 16),
            (las_u32p)(dst + cbase * 16), 16, 0, 0);
      }
    }
    cb = (cb == 2) ? 0 : cb + 1;
    sb = (sb == 2) ? 0 : sb + 1;

    // ================= odd half: kc = 2s+1 =================
    asm volatile("s_waitcnt vmcnt(12)" ::: "memory");
    asm volatile("s_barrier" ::: "memory");
    {
      bf16x8 ah[2], al[2];
#pragma unroll
      for (int rs = 0; rs < 2; ++rs)
#pragma unroll
        for (int e = 0; e < 8; ++e) {
          float f = a_cur[rs][8 + e];
          __bf16 h = (__bf16)f;
          ah[rs][e] = h;
          al[rs][e] = (__bf16)(f - (float)h);
        }
      const char* cur = lds + cb * 16384;
#pragma unroll
      for (int ct = 0; ct < 8; ++ct) {
        const int r   = ct * 16 + ncol;
        const int swz = r & 7;
        bf16x8 bh = *(const bf16x8*)(cur + (size_t)(r * 8 + (kg ^ swz)) * 16);
        bf16x8 bl = *(const bf16x8*)(cur + (size_t)(r * 8 + ((4 + kg) ^ swz)) * 16);
#pragma unroll
        for (int rs = 0; rs < 2; ++rs) {
          acc[rs][ct] = __builtin_amdgcn_mfma_f32_16x16x32_bf16(ah[rs], bh, acc[rs][ct], 0, 0, 0);
          acc[rs][ct] = __builtin_amdgcn_mfma_f32_16x16x32_bf16(al[rs], bh, acc[rs][ct], 0, 0, 0);
          acc[rs][ct] = __builtin_amdgcn_mfma_f32_16x16x32_bf16(ah[rs], bl, acc[rs][ct], 0, 0, 0);
        }
      }
    }
    // stage(2s+3) (4 ops; &15 wrap)
    {
      const char* gsrc = WpB + (size_t)((2 * s + 3) & 15) * 16384;
      char* dst = lds + sb * 16384;
#pragma unroll
      for (int i = 0; i < 4; ++i) {
        const int cbase = (wid * 4 + i) * 64;
        __builtin_amdgcn_global_load_lds(
            (gas_u32p)(gsrc + (size_t)(cbase + lane) * 16),
            (las_u32p)(dst + cbase * 16), 16, 0, 0);
      }
    }
    // rotate A chunk (renamed away under unroll)
#pragma unroll
    for (int rs = 0; rs < 2; ++rs)
#pragma unroll
      for (int e = 0; e < 16; ++e) a_cur[rs][e] = a_nxt[rs][e];
    cb = (cb == 2) ? 0 : cb + 1;
    sb = (sb == 2) ? 0 : sb + 1;
  }

  // epilogue: + bias, write out, side-reduce tile sum (for threshold)
  // C/D layout (m89): col = lane&15, row = (lane>>4)*4 + reg
  double lsum = 0.0;
#pragma unroll
  for (int rs = 0; rs < 2; ++rs) {
    const int orow0 = blockIdx.x * 128 + wid * 32 + rs * 16 + kg * 4;
#pragma unroll
    for (int ct = 0; ct < 8; ++ct) {
      float bv = bias[ct * 16 + ncol];
#pragma unroll
      for (int r = 0; r < 4; ++r) {
        float v = acc[rs][ct][r] + bv;
        out[(size_t)(orow0 + r) * ODIM + ct * 16 + ncol] = v;
        lsum += (double)v;
      }
    }
  }
#pragma unroll
  for (int off = 32; off; off >>= 1) lsum += __shfl_xor(lsum, off);
  __shared__ double wpart[4];
  if (lane == 0) wpart[wid] = lsum;
  __syncthreads();
  if (threadIdx.x == 0)
    partials[blockIdx.x] = wpart[0] + wpart[1] + wpart[2] + wpart[3];
}

// ---------------- threshold (redundant per block) ----------------
__device__ inline float compute_threshold(const double* __restrict__ partials,
                                          double* __restrict__ red) {
  double s = 0.0;
  for (int j = threadIdx.x; j < 2048; j += 256) s += partials[j];
  red[threadIdx.x] = s;
  __syncthreads();
  for (int st = 128; st; st >>= 1) {
    if ((int)threadIdx.x < st) red[threadIdx.x] += red[threadIdx.x + st];
    __syncthreads();
  }
  return (float)(red[0] / (double)NROWS);
}

__global__ __launch_bounds__(256) void count_kernel(
    const float* __restrict__ mask, const double* __restrict__ partials,
    int* __restrict__ counts, float* __restrict__ idx_out) {
  __shared__ double red[256];
  float thr = compute_threshold(partials, red);

  int base = blockIdx.x * 1024 + threadIdx.x * 4;
  float4 m = *(const float4*)(mask + base);
  int c = (m.x > thr) + (m.y > thr) + (m.z > thr) + (m.w > thr);
  *(float4*)(idx_out + base) = (float4){-1.f, -1.f, -1.f, -1.f};

  __shared__ int ired[256];
  ired[threadIdx.x] = c;
  __syncthreads();
  for (int st = 128; st; st >>= 1) {
    if ((int)threadIdx.x < st) ired[threadIdx.x] += ired[threadIdx.x + st];
    __syncthreads();
  }
  if (threadIdx.x == 0) counts[blockIdx.x] = ired[0];
}

// ---------------- exclusive scan of block counts (1 block) ----------------
__global__ __launch_bounds__(256) void scan_kernel(
    const int* __restrict__ counts, int* __restrict__ offsets) {
  __shared__ int tmp[256];
  int tid = threadIdx.x;
  int v = counts[tid];
  tmp[tid] = v;
  __syncthreads();
#pragma unroll
  for (int st = 1; st < 256; st <<= 1) {
    int t = (tid >= st) ? tmp[tid - st] : 0;
    __syncthreads();
    tmp[tid] += t;
    __syncthreads();
  }
  offsets[tid] = tmp[tid] - v;  // exclusive prefix
}

// ---------------- ordered scatter ----------------
__global__ __launch_bounds__(256) void scatter_kernel(
    const float* __restrict__ mask, const double* __restrict__ partials,
    const int* __restrict__ offsets, float* __restrict__ idx_out) {
  __shared__ double red[256];
  float thr = compute_threshold(partials, red);  // bit-identical to count_kernel

  int base = blockIdx.x * 1024 + threadIdx.x * 4;
  float4 m = *(const float4*)(mask + base);
  int p0 = m.x > thr, p1 = m.y > thr, p2 = m.z > thr, p3 = m.w > thr;
  int tc = p0 + p1 + p2 + p3;

  int lane = threadIdx.x & 63, wv = threadIdx.x >> 6;
  int incl = tc;
#pragma unroll
  for (int off = 1; off < 64; off <<= 1) {
    int v = __shfl_up(incl, off);
    if (lane >= off) incl += v;
  }
  __shared__ int wsum[4];
  if (lane == 63) wsum[wv] = incl;
  __syncthreads();
  int wbase = 0;
  for (int w = 0; w < wv; ++w) wbase += wsum[w];

  int pos = offsets[blockIdx.x] + wbase + (incl - tc);
  if (p0) idx_out[pos++] = (float)(base + 0);
  if (p1) idx_out[pos++] = (float)(base + 1);
  if (p2) idx_out[pos++] = (float)(base + 2);
  if (p3) idx_out[pos++] = (float)(base + 3);
}

extern "C" void kernel_launch(void* const* d_in, const int* in_sizes, int n_in,
                              void* d_out, int out_size, void* d_ws, size_t ws_size,
                              hipStream_t stream) {
  const float* x    = (const float*)d_in[0];
  const float* mask = (const float*)d_in[1];
  const float* W    = (const float*)d_in[2];
  const float* bias = (const float*)d_in[3];

  float* out     = (float*)d_out;
  float* idx_out = out + (size_t)NROWS * ODIM;

  char*   ws       = (char*)d_ws;
  char*   WpB      = ws;
  double* partials = (double*)(ws + 262144);
  int*    counts   = (int*)(ws + 278528);
  int*    offsets  = (int*)(ws + 279552);

  convert_w_kernel<<<32, 256, 0, stream>>>(W, WpB);
  gemm_kernel<<<2048, 256, 0, stream>>>(x, WpB, bias, out, partials);
  count_kernel<<<256, 256, 0, stream>>>(mask, partials, counts, idx_out);
  scan_kernel<<<1, 256, 0, stream>>>(counts, offsets);
  scatter_kernel<<<256, 256, 0, stream>>>(mask, partials, offsets, idx_out);
}

// Round 12
// 753.124 us; speedup vs baseline: 1.1590x; 1.1590x over previous
//
#include <hip/hip_runtime.h>

#define NROWS 262144
#define KDIM  512
#define ODIM  128

typedef __attribute__((ext_vector_type(8))) __bf16 bf16x8;
typedef __attribute__((ext_vector_type(4))) float  f32x4;

typedef __attribute__((address_space(1))) const unsigned int* gas_u32p;
typedef __attribute__((address_space(3))) unsigned int*       las_u32p;

// ---- workspace layout (bytes) ----
// [0      , 262144): Wp  packed split-bf16 W, 16 kc-slices x 16KB.
//   slice kc holds 1024 chunks of 16B; chunk for (row r, hl, kg) at index
//   r*8 + ((hl*4+kg) ^ (r&7))  [XOR swizzle baked into GLOBAL layout so the
//   LDS staging copy is linear and ds_read_b128 is bank-conflict-free]
//   chunk data: bf16 of W[r][kc*32+kg*8 .. +8] (hl=0: hi, hl=1: residual lo)
// [262144, 278528): partials double[2048]
// [278528, 279552): counts  int[256]
// [279552, 280576): offsets int[256]

// R11 post-mortem: A-chunking (R10) regressed 755->873 -- the +64-VGPR A
// double-buffer exceeded the (256,3) budget and spilled in the K-loop.
// Reverted to the R9-benched kernel (755.2us, GEMM ~190us). At (256,3) this
// kernel has ~zero VGPR headroom: do NOT widen per-thread buffers.

// ---------------- W pre-convert: fp32 -> packed swizzled (hi,lo) ----------------
__global__ __launch_bounds__(256) void convert_w_kernel(
    const float* __restrict__ W, char* __restrict__ WpB) {
  int gid = blockIdx.x * 256 + threadIdx.x;  // 8192 threads: kc(16) x r(128) x kg(4)
  int kg = gid & 3, r = (gid >> 2) & 127, kc = gid >> 9;
  const float4* src = (const float4*)(W + (size_t)r * KDIM + kc * 32 + kg * 8);
  float4 v0 = src[0], v1 = src[1];
  float f[8] = {v0.x, v0.y, v0.z, v0.w, v1.x, v1.y, v1.z, v1.w};
  bf16x8 h, l;
#pragma unroll
  for (int e = 0; e < 8; ++e) {
    __bf16 hh = (__bf16)f[e];
    h[e] = hh;
    l[e] = (__bf16)(f[e] - (float)hh);  // residual exact in fp32, then RNE
  }
  char* slice = WpB + (size_t)kc * 16384 + r * 128;  // r*8 chunks * 16B
  int swz = r & 7;
  *(bf16x8*)(slice + ((kg ^ swz)) * 16)       = h;
  *(bf16x8*)(slice + (((4 + kg) ^ swz)) * 16) = l;
}

// ---------------- GEMM: out = x @ W^T + b, split-bf16 3-MFMA ----------------
// R6/R9 structure: 3 LDS buffers (48KB), one raw s_barrier per iter, uniform
// s_waitcnt vmcnt(8): slice kc+1 + loadA(kc+1) stay in flight across the
// barrier. Per-wave vm-op ledger at wait(kc): outstanding = {stage(kc) 4,
// loadA(kc) 4, stage(kc+1) 4, loadA(kc+1) 4} = 16 -> vmcnt(8) forces exactly
// the oldest 8 {stage(kc), loadA(kc)}. Race audit: stage(kc+2) (program-order
// after barrier(kc)) targets buf (kc+2)%3 whose last readers (compute kc-1)
// preceded barrier(kc) in every wave; tail dummy stages hit only dead
// buffers. Numerics identical to R2/R5/R9 benched lineage (absmax 0.015625).
__global__ __launch_bounds__(256, 3) void gemm_kernel(
    const float* __restrict__ x, const char* __restrict__ WpB,
    const float* __restrict__ bias, float* __restrict__ out,
    double* __restrict__ partials) {
  const int lane = threadIdx.x & 63;
  const int wid  = threadIdx.x >> 6;
  const int ncol = lane & 15;
  const int kg   = lane >> 4;  // k-subgroup 0..3 (8 elems each)

  __shared__ __align__(16) char lds[49152];  // 3 x 16KB B-slice buffers

  const int row0 = blockIdx.x * 128 + wid * 32 + ncol;  // A rows, subtile 0
  const float* xrow0 = x + (size_t)row0 * KDIM + kg * 8;
  const float* xrow1 = xrow0 + (size_t)16 * KDIM;

  f32x4 acc[2][8];
#pragma unroll
  for (int rs = 0; rs < 2; ++rs)
#pragma unroll
    for (int ct = 0; ct < 8; ++ct) acc[rs][ct] = (f32x4){0.f, 0.f, 0.f, 0.f};

  // ---- prologue: loadA(0); stage slice0->buf0; stage slice1->buf1 ----
  float a_cur[2][8];
#pragma unroll
  for (int rs = 0; rs < 2; ++rs) {
    const float4* p = (const float4*)(rs ? xrow1 : xrow0);
    float4 v0 = p[0], v1 = p[1];
    a_cur[rs][0] = v0.x; a_cur[rs][1] = v0.y; a_cur[rs][2] = v0.z; a_cur[rs][3] = v0.w;
    a_cur[rs][4] = v1.x; a_cur[rs][5] = v1.y; a_cur[rs][6] = v1.z; a_cur[rs][7] = v1.w;
  }
#pragma unroll
  for (int s = 0; s < 2; ++s) {
#pragma unroll
    for (int i = 0; i < 4; ++i) {
      const int cbase = (wid * 4 + i) * 64;  // wave-uniform chunk base
      __builtin_amdgcn_global_load_lds(
          (gas_u32p)(WpB + (size_t)s * 16384 + (size_t)(cbase + lane) * 16),
          (las_u32p)(lds + s * 16384 + cbase * 16), 16, 0, 0);
    }
  }

  int cb = 0;  // compute buffer = kc%3
  int sb = 2;  // stage buffer   = (kc+2)%3
#pragma unroll 2
  for (int kc = 0; kc < 16; ++kc) {
    // loadA(kc+1): next A chunk into regs (clamped redundant load on last iter)
    float a_nxt[2][8];
    {
      const int kn = (kc < 15) ? (kc * 32 + 32) : kc * 32;
#pragma unroll
      for (int rs = 0; rs < 2; ++rs) {
        const float4* p = (const float4*)((rs ? xrow1 : xrow0) + kn);
        float4 v0 = p[0], v1 = p[1];
        a_nxt[rs][0] = v0.x; a_nxt[rs][1] = v0.y; a_nxt[rs][2] = v0.z; a_nxt[rs][3] = v0.w;
        a_nxt[rs][4] = v1.x; a_nxt[rs][5] = v1.y; a_nxt[rs][6] = v1.z; a_nxt[rs][7] = v1.w;
      }
    }
    // wait: forces {stage(kc), loadA(kc)} done; keeps {stage(kc+1), loadA(kc+1)}
    // in flight. Then barrier -> every wave's quarter of buf kc%3 is complete.
    asm volatile("s_waitcnt vmcnt(8)" ::: "memory");
    asm volatile("s_barrier" ::: "memory");

    // split-convert current A chunk to hi/lo bf16
    bf16x8 ah[2], al[2];
#pragma unroll
    for (int rs = 0; rs < 2; ++rs)
#pragma unroll
      for (int e = 0; e < 8; ++e) {
        float f = a_cur[rs][e];
        __bf16 h = (__bf16)f;
        ah[rs][e] = h;
        al[rs][e] = (__bf16)(f - (float)h);
      }
    // MFMA over 8 col-tiles; B frags from LDS (swizzled addr, 2-way max)
    const char* cur = lds + cb * 16384;
#pragma unroll
    for (int ct = 0; ct < 8; ++ct) {
      const int r   = ct * 16 + ncol;
      const int swz = r & 7;
      bf16x8 bh = *(const bf16x8*)(cur + (size_t)(r * 8 + (kg ^ swz)) * 16);
      bf16x8 bl = *(const bf16x8*)(cur + (size_t)(r * 8 + ((4 + kg) ^ swz)) * 16);
#pragma unroll
      for (int rs = 0; rs < 2; ++rs) {
        acc[rs][ct] = __builtin_amdgcn_mfma_f32_16x16x32_bf16(ah[rs], bh, acc[rs][ct], 0, 0, 0);
        acc[rs][ct] = __builtin_amdgcn_mfma_f32_16x16x32_bf16(al[rs], bh, acc[rs][ct], 0, 0, 0);
        acc[rs][ct] = __builtin_amdgcn_mfma_f32_16x16x32_bf16(ah[rs], bl, acc[rs][ct], 0, 0, 0);
      }
    }
    // stage(kc+2) into buf (kc+2)%3: safe -- its last readers were compute
    // kc-1, and all waves passed barrier(kc) (program-order after it) before
    // any wave reaches this point. Tail iters stage dummy slices (&15 wrap)
    // into dead buffers to keep the vmcnt ledger uniform.
    {
      const char* gsrc = WpB + (size_t)((kc + 2) & 15) * 16384;
      char* dst = lds + sb * 16384;
#pragma unroll
      for (int i = 0; i < 4; ++i) {
        const int cbase = (wid * 4 + i) * 64;
        __builtin_amdgcn_global_load_lds(
            (gas_u32p)(gsrc + (size_t)(cbase + lane) * 16),
            (las_u32p)(dst + cbase * 16), 16, 0, 0);
      }
    }
#pragma unroll
    for (int rs = 0; rs < 2; ++rs)
#pragma unroll
      for (int e = 0; e < 8; ++e) a_cur[rs][e] = a_nxt[rs][e];
    cb = (cb == 2) ? 0 : cb + 1;
    sb = (sb == 2) ? 0 : sb + 1;
  }

  // epilogue: + bias, write out, side-reduce tile sum (for threshold)
  // C/D layout (m89): col = lane&15, row = (lane>>4)*4 + reg
  double lsum = 0.0;
#pragma unroll
  for (int rs = 0; rs < 2; ++rs) {
    const int orow0 = blockIdx.x * 128 + wid * 32 + rs * 16 + kg * 4;
#pragma unroll
    for (int ct = 0; ct < 8; ++ct) {
      float bv = bias[ct * 16 + ncol];
#pragma unroll
      for (int r = 0; r < 4; ++r) {
        float v = acc[rs][ct][r] + bv;
        out[(size_t)(orow0 + r) * ODIM + ct * 16 + ncol] = v;
        lsum += (double)v;
      }
    }
  }
#pragma unroll
  for (int off = 32; off; off >>= 1) lsum += __shfl_xor(lsum, off);
  __shared__ double wpart[4];
  if (lane == 0) wpart[wid] = lsum;
  __syncthreads();
  if (threadIdx.x == 0)
    partials[blockIdx.x] = wpart[0] + wpart[1] + wpart[2] + wpart[3];
}

// ---------------- threshold (redundant per block) ----------------
__device__ inline float compute_threshold(const double* __restrict__ partials,
                                          double* __restrict__ red) {
  double s = 0.0;
  for (int j = threadIdx.x; j < 2048; j += 256) s += partials[j];
  red[threadIdx.x] = s;
  __syncthreads();
  for (int st = 128; st; st >>= 1) {
    if ((int)threadIdx.x < st) red[threadIdx.x] += red[threadIdx.x + st];
    __syncthreads();
  }
  return (float)(red[0] / (double)NROWS);
}

__global__ __launch_bounds__(256) void count_kernel(
    const float* __restrict__ mask, const double* __restrict__ partials,
    int* __restrict__ counts, float* __restrict__ idx_out) {
  __shared__ double red[256];
  float thr = compute_threshold(partials, red);

  int base = blockIdx.x * 1024 + threadIdx.x * 4;
  float4 m = *(const float4*)(mask + base);
  int c = (m.x > thr) + (m.y > thr) + (m.z > thr) + (m.w > thr);
  *(float4*)(idx_out + base) = (float4){-1.f, -1.f, -1.f, -1.f};

  __shared__ int ired[256];
  ired[threadIdx.x] = c;
  __syncthreads();
  for (int st = 128; st; st >>= 1) {
    if ((int)threadIdx.x < st) ired[threadIdx.x] += ired[threadIdx.x + st];
    __syncthreads();
  }
  if (threadIdx.x == 0) counts[blockIdx.x] = ired[0];
}

// ---------------- exclusive scan of block counts (1 block) ----------------
__global__ __launch_bounds__(256) void scan_kernel(
    const int* __restrict__ counts, int* __restrict__ offsets) {
  __shared__ int tmp[256];
  int tid = threadIdx.x;
  int v = counts[tid];
  tmp[tid] = v;
  __syncthreads();
#pragma unroll
  for (int st = 1; st < 256; st <<= 1) {
    int t = (tid >= st) ? tmp[tid - st] : 0;
    __syncthreads();
    tmp[tid] += t;
    __syncthreads();
  }
  offsets[tid] = tmp[tid] - v;  // exclusive prefix
}

// ---------------- ordered scatter ----------------
__global__ __launch_bounds__(256) void scatter_kernel(
    const float* __restrict__ mask, const double* __restrict__ partials,
    const int* __restrict__ offsets, float* __restrict__ idx_out) {
  __shared__ double red[256];
  float thr = compute_threshold(partials, red);  // bit-identical to count_kernel

  int base = blockIdx.x * 1024 + threadIdx.x * 4;
  float4 m = *(const float4*)(mask + base);
  int p0 = m.x > thr, p1 = m.y > thr, p2 = m.z > thr, p3 = m.w > thr;
  int tc = p0 + p1 + p2 + p3;

  int lane = threadIdx.x & 63, wv = threadIdx.x >> 6;
  int incl = tc;
#pragma unroll
  for (int off = 1; off < 64; off <<= 1) {
    int v = __shfl_up(incl, off);
    if (lane >= off) incl += v;
  }
  __shared__ int wsum[4];
  if (lane == 63) wsum[wv] = incl;
  __syncthreads();
  int wbase = 0;
  for (int w = 0; w < wv; ++w) wbase += wsum[w];

  int pos = offsets[blockIdx.x] + wbase + (incl - tc);
  if (p0) idx_out[pos++] = (float)(base + 0);
  if (p1) idx_out[pos++] = (float)(base + 1);
  if (p2) idx_out[pos++] = (float)(base + 2);
  if (p3) idx_out[pos++] = (float)(base + 3);
}

extern "C" void kernel_launch(void* const* d_in, const int* in_sizes, int n_in,
                              void* d_out, int out_size, void* d_ws, size_t ws_size,
                              hipStream_t stream) {
  const float* x    = (const float*)d_in[0];
  const float* mask = (const float*)d_in[1];
  const float* W    = (const float*)d_in[2];
  const float* bias = (const float*)d_in[3];

  float* out     = (float*)d_out;
  float* idx_out = out + (size_t)NROWS * ODIM;

  char*   ws       = (char*)d_ws;
  char*   WpB      = ws;
  double* partials = (double*)(ws + 262144);
  int*    counts   = (int*)(ws + 278528);
  int*    offsets  = (int*)(ws + 279552);

  convert_w_kernel<<<32, 256, 0, stream>>>(W, WpB);
  gemm_kernel<<<2048, 256, 0, stream>>>(x, WpB, bias, out, partials);
  count_kernel<<<256, 256, 0, stream>>>(mask, partials, counts, idx_out);
  scan_kernel<<<1, 256, 0, stream>>>(counts, offsets);
  scatter_kernel<<<256, 256, 0, stream>>>(mask, partials, offsets, idx_out);
}